// Round 8
// baseline (3186814.453 us; speedup 1.0000x reference)
//
#include <hip/hip_runtime.h>
#include <math.h>

#define B_     128
#define L_     100
#define HID_   256
#define IND_   160
#define NCLASS 19
#define CAPD   16
#define NI     1600      // L_ * NUM_CAPS
#define OD     304       // NCLASS * CAPD
#define ENTITY 68

// ---------------------------------------------------------------------------
// Phase 0: embedding gather -> emb [b*L_+t][160]
// ---------------------------------------------------------------------------
__global__ void emb_gather(const int* __restrict__ word, const int* __restrict__ tag,
                           const int* __restrict__ pos1, const int* __restrict__ pos2,
                           const float* __restrict__ we, const float* __restrict__ te,
                           const float* __restrict__ p1e, const float* __restrict__ p2e,
                           float* __restrict__ emb)
{
    int idx = blockIdx.x * 256 + threadIdx.x;          // exactly B_*L_*IND_ threads
    int bt = idx / IND_;
    int k  = idx - bt * IND_;
    float v;
    if (k < 100)      v = we[word[bt] * 100 + k];
    else if (k < 120) v = te[tag[bt] * 20 + (k - 100)];
    else if (k < 140) v = p1e[pos1[bt] * 20 + (k - 120)];
    else              v = p2e[pos2[bt] * 20 + (k - 140)];
    emb[idx] = v;
}

// ---------------------------------------------------------------------------
// Phase 1: input-gate GEMM.
// xg layout (cluster-friendly): [dir][t][bg(32)][jq(4)][g(4)][jl(64)][bl(4)]
// ---------------------------------------------------------------------------
__global__ void __launch_bounds__(256) gemm_xg(
    const float* __restrict__ emb,
    const float* __restrict__ wihf, const float* __restrict__ bihf, const float* __restrict__ bhhf,
    const float* __restrict__ wihb, const float* __restrict__ bihb, const float* __restrict__ bhhb,
    float* __restrict__ xg)
{
    int gt  = blockIdx.x;
    int t   = blockIdx.y;
    int dir = blockIdx.z;
    const float* w  = dir ? wihb : wihf;
    const float* bi = dir ? bihb : bihf;
    const float* bh = dir ? bhhb : bhhf;
    int gj0 = gt * 128;

    __shared__ float wsh[32][132];   // [k][gj], padded
    __shared__ float esh[32][132];   // [k][b],  padded

    int tid = threadIdx.x;
    int tx = tid & 15, ty = tid >> 4;

    float acc[8][8];
    #pragma unroll
    for (int i = 0; i < 8; ++i)
        #pragma unroll
        for (int j = 0; j < 8; ++j) acc[i][j] = 0.f;

    for (int k0 = 0; k0 < IND_; k0 += 32) {
        __syncthreads();
        #pragma unroll
        for (int m = 0; m < 16; ++m) {
            int e = m * 256 + tid;        // 0..4095
            int k = e & 31, g = e >> 5;   // g: row (gj or b)
            wsh[k][g] = w[(gj0 + g) * IND_ + k0 + k];
            esh[k][g] = emb[(g * L_ + t) * IND_ + k0 + k];
        }
        __syncthreads();
        #pragma unroll
        for (int k = 0; k < 32; ++k) {
            float wv[8], ev[8];
            #pragma unroll
            for (int q = 0; q < 8; ++q) wv[q] = wsh[k][ty * 8 + q];
            #pragma unroll
            for (int q = 0; q < 8; ++q) ev[q] = esh[k][tx * 8 + q];
            #pragma unroll
            for (int i = 0; i < 8; ++i)
                #pragma unroll
                for (int j = 0; j < 8; ++j) acc[i][j] = fmaf(wv[i], ev[j], acc[i][j]);
        }
    }
    #pragma unroll
    for (int i = 0; i < 8; ++i) {
        int gj = gj0 + ty * 8 + i;
        float bias = bi[gj] + bh[gj];
        int g = gj >> 8, jf = gj & 255;
        #pragma unroll
        for (int j = 0; j < 8; ++j) {
            int b = tx * 8 + j;
            size_t idx = ((((size_t)dir * L_ + t) * 32 + (b >> 2)) * 4 + (jf >> 6)) * 1024
                       + g * 256 + (jf & 63) * 4 + (b & 3);
            xg[idx] = acc[i][j] + bias;
        }
    }
}

// ---------------------------------------------------------------------------
// Phase 2: BiLSTM scan v8 — LDS-RESIDENT weights (DYNAMIC LDS), 4-block
// clusters, cooperative. blk = jq*64 + dir*32 + bg. Block owns a j-quarter
// (64 j) for 4 batches; weights 4g x 64j x 256k bf16 in 135168 B dynamic LDS
// (528 B row stride = conflict-optimal for the (jl,kc) b128 read pattern).
// Thread (jl = tid>>3, kc = tid&7) covers k in [kc*32, kc*32+32). Per step:
// dot from LDS, shfl-reduce over kc, kc0 lanes do activations, publish the
// h-quarter via agent-scope stores (bypass per-XCD L2), release flag;
// partners spin (bounded) + acquire, gather. h in LDS, 132-float skew.
// ---------------------------------------------------------------------------
__device__ __forceinline__ float sigm_f(float x) { return 1.f / (1.f + __expf(-x)); }
__device__ __forceinline__ float tanh_f(float x) {
    float e = __expf(-2.f * fabsf(x));        // in (0,1], never overflows
    float r = (1.f - e) / (1.f + e);
    return copysignf(r, x);
}
__device__ __forceinline__ unsigned short f2bf(float f) {
    unsigned u = __float_as_uint(f);
    return (unsigned short)((u + 0x7fffu + ((u >> 16) & 1u)) >> 16);   // RNE
}
__device__ __forceinline__ unsigned packbf2(float lo, float hi) {
    return (unsigned)f2bf(lo) | ((unsigned)f2bf(hi) << 16);
}
#define BFLO(w) __uint_as_float((w) << 16)
#define BFHI(w) __uint_as_float((w) & 0xffff0000u)

__global__ void __launch_bounds__(512) lstm_scan_h(
    const float* __restrict__ xg,
    const float* __restrict__ whhf, const float* __restrict__ whhb,
    float* xf, float* xb, int* flags)
{
    extern __shared__ __align__(16) unsigned char wlds[];   // 4*64*528 = 135168 B

    int blk = blockIdx.x;              // 0..255
    int dir = (blk >> 5) & 1;
    int bg  = blk & 31;
    int jq  = blk >> 6;
    int tid = threadIdx.x;
    int kc  = tid & 7;                 // k-chunk 0..7 (low 3 lane bits)
    int jl  = tid >> 3;                // 0..63

    const float* whh = dir ? whhb : whhf;
    float* xo = dir ? xb : xf;
    const int fbase = (dir * 32 + bg) * 4;

    __shared__ __align__(16) float hfull[2][1056];          // 2 x 4224 B, skewed

    // ---- one-time weight preload: fp32 d_in -> bf16 packed LDS ----
    {
        int r = tid >> 1, hh = tid & 1;       // r 0..255 = (g,jl); hh = k-half
        int g = r >> 6, jj = r & 63;
        const float4* src = (const float4*)(whh + ((size_t)(g * 256 + jq * 64 + jj)) * 256 + hh * 128);
        unsigned* dst = (unsigned*)(wlds + (g * 64 + jj) * 528 + hh * 256);
        #pragma unroll
        for (int q = 0; q < 32; ++q) {
            float4 f = src[q];
            dst[2 * q]     = packbf2(f.x, f.y);
            dst[2 * q + 1] = packbf2(f.z, f.w);
        }
        for (int z = tid; z < 2 * 1056; z += 512) ((float*)hfull)[z] = 0.f;
    }
    float cst[4] = { 0.f, 0.f, 0.f, 0.f };     // cell state (kc0 lanes), 4 batches
    __syncthreads();

    for (int t = 0; t < L_; ++t) {
        int slot = dir ? (L_ - 1 - t) : t;
        int par = t & 1;

        // xg prefetch (kc0 lanes only; independent of h)
        float4 xgv[4];
        if (kc == 0) {
            const float* xp = xg + ((((size_t)dir * L_ + slot) * 32 + bg) * 4 + jq) * 1024 + jl * 4;
            xgv[0] = *(const float4*)(xp);
            xgv[1] = *(const float4*)(xp + 256);
            xgv[2] = *(const float4*)(xp + 512);
            xgv[3] = *(const float4*)(xp + 768);
        }

        // dot product: a[g][b] over this thread's 32 k
        float a[4][4];
        #pragma unroll
        for (int g = 0; g < 4; ++g)
            #pragma unroll
            for (int b = 0; b < 4; ++b) a[g][b] = 0.f;

        const float* hpar = hfull[par] + kc * 132;
        #pragma unroll
        for (int i = 0; i < 4; ++i) {
            const float4* hp = (const float4*)(hpar + i * 32);
            float4 hk[8];
            #pragma unroll
            for (int e = 0; e < 8; ++e) hk[e] = hp[e];
            #pragma unroll
            for (int g = 0; g < 4; ++g) {
                uint4 wv = *(const uint4*)(wlds + (g * 64 + jl) * 528 + kc * 64 + i * 16);
                unsigned uu[4] = { wv.x, wv.y, wv.z, wv.w };
                #pragma unroll
                for (int p2 = 0; p2 < 4; ++p2) {
                    float wlo = BFLO(uu[p2]), whi = BFHI(uu[p2]);
                    float4 hA = hk[2 * p2], hB = hk[2 * p2 + 1];
                    a[g][0] = fmaf(wlo, hA.x, a[g][0]);
                    a[g][1] = fmaf(wlo, hA.y, a[g][1]);
                    a[g][2] = fmaf(wlo, hA.z, a[g][2]);
                    a[g][3] = fmaf(wlo, hA.w, a[g][3]);
                    a[g][0] = fmaf(whi, hB.x, a[g][0]);
                    a[g][1] = fmaf(whi, hB.y, a[g][1]);
                    a[g][2] = fmaf(whi, hB.z, a[g][2]);
                    a[g][3] = fmaf(whi, hB.w, a[g][3]);
                }
            }
        }
        // reduce over the 8 kc lanes (xor 1,2,4 — in-wave)
        #pragma unroll
        for (int g = 0; g < 4; ++g)
            #pragma unroll
            for (int b = 0; b < 4; ++b) {
                a[g][b] += __shfl_xor(a[g][b], 1);
                a[g][b] += __shfl_xor(a[g][b], 2);
                a[g][b] += __shfl_xor(a[g][b], 4);
            }

        if (kc == 0) {
            float hv[4];
            #pragma unroll
            for (int b = 0; b < 4; ++b) {
                float ai = a[0][b] + ((const float*)&xgv[0])[b];
                float af = a[1][b] + ((const float*)&xgv[1])[b];
                float ag = a[2][b] + ((const float*)&xgv[2])[b];
                float ao = a[3][b] + ((const float*)&xgv[3])[b];
                float ig = sigm_f(ai), fg = sigm_f(af), gg = tanh_f(ag), og = sigm_f(ao);
                cst[b] = fg * cst[b] + ig * gg;
                hv[b] = og * tanh_f(cst[b]);
            }
            // publish h-quarter: agent-scope stores (bypass per-XCD L2)
            float* xop = xo + (((size_t)slot * 32 + bg) * 4 + jq) * 256 + jl * 4;
            #pragma unroll
            for (int b = 0; b < 4; ++b)
                __hip_atomic_store(xop + b, hv[b], __ATOMIC_RELAXED, __HIP_MEMORY_SCOPE_AGENT);
            // own quarter into next h buffer (LDS, skewed)
            int k = jq * 64 + jl;
            float* hd = hfull[par ^ 1] + k * 4 + (k >> 5) * 4;
            #pragma unroll
            for (int b = 0; b < 4; ++b) hd[b] = hv[b];
        }
        __builtin_amdgcn_s_waitcnt(0);     // each thread's global stores drained
        __syncthreads();

        if (t < L_ - 1) {
            if (tid == 0) {
                __hip_atomic_store(&flags[fbase + jq], t + 1,
                                   __ATOMIC_RELEASE, __HIP_MEMORY_SCOPE_AGENT);
            } else if (tid <= 3) {
                int p = tid - 1;
                int pjq = p + (p >= jq);
                const int* pf = &flags[fbase + pjq];
                int spin = 0;
                while (__hip_atomic_load(pf, __ATOMIC_RELAXED, __HIP_MEMORY_SCOPE_AGENT) < t + 1) {
                    __builtin_amdgcn_s_sleep(2);
                    if (++spin > 200000) break;    // bounded: fail loud, never hang
                }
                (void)__hip_atomic_load(pf, __ATOMIC_ACQUIRE, __HIP_MEMORY_SCOPE_AGENT);
            }
            __syncthreads();
            // gather 3 partner quarters (768 floats) into hfull[par^1]
            if (tid < 384) {
                int p = tid >> 7;
                int pjq = p + (p >= jq);
                int off = tid & 127;                 // float2 index within quarter
                const float* srcq = xo + (((size_t)slot * 32 + bg) * 4 + pjq) * 256 + off * 2;
                float v0 = __hip_atomic_load(srcq,     __ATOMIC_RELAXED, __HIP_MEMORY_SCOPE_AGENT);
                float v1 = __hip_atomic_load(srcq + 1, __ATOMIC_RELAXED, __HIP_MEMORY_SCOPE_AGENT);
                int jl2 = off >> 1, pr = off & 1;
                int k = pjq * 64 + jl2;
                float* hd = hfull[par ^ 1] + k * 4 + (k >> 5) * 4 + pr * 2;
                hd[0] = v0; hd[1] = v1;
            }
            __syncthreads();
        }
    }
}

__global__ void zero_flags(int* f) { f[threadIdx.x] = 0; }   // 256 threads

// ---------------------------------------------------------------------------
// x[l][j][b] = xf + xb  (inputs in cluster layout [l][bg][jq][jl][bl])
// ---------------------------------------------------------------------------
__global__ void xpose_add(const float* __restrict__ xf, const float* __restrict__ xb,
                          float* __restrict__ x)
{
    int idx = blockIdx.x * 256 + threadIdx.x;   // exactly L_*HID_*B_ threads
    int b = idx & 127;
    int r = idx >> 7;
    int j = r & 255;
    int l = r >> 8;
    int src = ((l * 32 + (b >> 2)) * 4 + (j >> 6)) * 256 + (j & 63) * 4 + (b & 3);
    x[idx] = xf[src] + xb[src];
}

// ---------------------------------------------------------------------------
// Phase 3: entity features, attention, primary capsules (x is [l][j][b])
// ---------------------------------------------------------------------------
__global__ void find_entity(const int* __restrict__ pos1, const int* __restrict__ pos2,
                            int* __restrict__ e)
{
    int b = threadIdx.x;
    int e1 = 0, e2 = 0;
    for (int l = L_ - 1; l >= 0; --l) if (pos1[b * L_ + l] == ENTITY) e1 = l;
    for (int l = L_ - 1; l >= 0; --l) if (pos2[b * L_ + l] == ENTITY) e2 = l;
    e[b] = e1; e[B_ + b] = e2;
}

__global__ void compute_he(const float* __restrict__ x, const int* __restrict__ e,
                           float* __restrict__ he)
{
    int j = blockIdx.x, b = threadIdx.x;
    int e1 = e[b], e2 = e[B_ + b];
    he[j * B_ + b] = x[((size_t)e1 * HID_ + j) * B_ + b] + x[((size_t)e2 * HID_ + j) * B_ + b];
}

__global__ void att_logits(const float* __restrict__ x, const float* __restrict__ he,
                           float* __restrict__ logits)
{
    int l = blockIdx.x, b = threadIdx.x;
    float acc = 0.f;
    for (int j = 0; j < HID_; ++j)
        acc = fmaf(x[((size_t)l * HID_ + j) * B_ + b], he[j * B_ + b], acc);
    logits[l * B_ + b] = acc;
}

__global__ void att_softmax(const float* __restrict__ logits, float* __restrict__ att)
{
    int b = threadIdx.x;
    float m = -1e30f;
    for (int l = 0; l < L_; ++l) m = fmaxf(m, logits[l * B_ + b]);
    float s = 0.f;
    for (int l = 0; l < L_; ++l) s += expf(logits[l * B_ + b] - m);
    float inv = 1.f / s;
    for (int l = 0; l < L_; ++l) att[l * B_ + b] = expf(logits[l * B_ + b] - m) * inv;
}

// primary capsules: u[i][b][c], squashed
__global__ void u_squash(const float* __restrict__ x, float* __restrict__ u)
{
    int i = blockIdx.x, b = threadIdx.x;
    int l = i >> 4, cap = i & 15;
    float vals[16]; float n2 = 0.f;
    #pragma unroll
    for (int c2 = 0; c2 < 16; ++c2) {
        float v = x[((size_t)l * HID_ + cap * 16 + c2) * B_ + b];
        vals[c2] = v; n2 = fmaf(v, v, n2);
    }
    float f = (n2 / (1.f + n2)) / sqrtf(n2 + 1e-9f);
    #pragma unroll
    for (int c2 = 0; c2 < 16; ++c2)
        u[((size_t)i * B_ + b) * 16 + c2] = vals[c2] * f;
}

// ---------------------------------------------------------------------------
// Phase 4: routing
// ---------------------------------------------------------------------------
__global__ void bb_init(const float* __restrict__ br, float* __restrict__ bb)
{
    int idx = blockIdx.x * 256 + threadIdx.x;   // exactly B_*NI*NCLASS threads
    bb[idx] = br[idx % (NI * NCLASS)];
}

__global__ void __launch_bounds__(320) s_pass(
    const float* __restrict__ u, const float* __restrict__ W,
    const float* __restrict__ bb, const float* __restrict__ att,
    float* __restrict__ partial)
{
    int ic = blockIdx.x, bt = blockIdx.y;
    int i0 = ic * 16, b0 = bt * 16;
    __shared__ float C[16][16][20];   // [bl][il][o], padded
    int tid = threadIdx.x;
    if (tid < 256) {
        int bl = tid >> 4, il = tid & 15;
        int b = b0 + bl, i = i0 + il;
        const float* bbp = bb + ((size_t)b * NI + i) * NCLASS;
        float m = bbp[0];
        #pragma unroll
        for (int o = 1; o < NCLASS; ++o) m = fmaxf(m, bbp[o]);
        float s = 0.f; float e[NCLASS];
        #pragma unroll
        for (int o = 0; o < NCLASS; ++o) { e[o] = expf(bbp[o] - m); s += e[o]; }
        float al = att[(i >> 4) * B_ + b] / s;
        #pragma unroll
        for (int o = 0; o < NCLASS; ++o) C[bl][il][o] = e[o] * al;
    }
    __syncthreads();
    if (tid >= OD) return;
    int od = tid, o = od >> 4;
    float acc[16];
    #pragma unroll
    for (int bl = 0; bl < 16; ++bl) acc[bl] = 0.f;
    for (int il = 0; il < 16; ++il) {
        int i = i0 + il;
        const float* wp = W + (size_t)i * 16 * OD + od;
        float w[16];
        #pragma unroll
        for (int c2 = 0; c2 < 16; ++c2) w[c2] = wp[c2 * OD];     // coalesced over od
        const float* up = u + ((size_t)i * B_ + b0) * 16;        // uniform -> s_load
        #pragma unroll
        for (int bl = 0; bl < 16; ++bl) {
            float uh = 0.f;
            #pragma unroll
            for (int c2 = 0; c2 < 16; ++c2) uh = fmaf(up[bl * 16 + c2], w[c2], uh);
            acc[bl] = fmaf(C[bl][il][o], uh, acc[bl]);
        }
    }
    #pragma unroll
    for (int bl = 0; bl < 16; ++bl)
        partial[((size_t)ic * B_ + b0 + bl) * OD + od] = acc[bl];
}

__global__ void s_reduce(const float* __restrict__ partial, float* __restrict__ s)
{
    int idx = blockIdx.x * 256 + threadIdx.x;   // exactly B_*OD threads
    int b = idx / OD, od = idx - b * OD;
    float acc = 0.f;
    for (int ic = 0; ic < 100; ++ic) acc += partial[((size_t)ic * B_ + b) * OD + od];
    s[idx] = acc;
}

__global__ void squash_v(const float* __restrict__ s, float* __restrict__ v,
                         float* __restrict__ out, int write_out)
{
    int idx = blockIdx.x * 256 + threadIdx.x;
    if (idx >= B_ * NCLASS) return;
    const float* sp = s + (size_t)idx * 16;     // b*304 + o*16 == idx*16
    float vals[16]; float n2 = 0.f;
    #pragma unroll
    for (int d = 0; d < 16; ++d) { vals[d] = sp[d]; n2 = fmaf(vals[d], vals[d], n2); }
    float f = (n2 / (1.f + n2)) / sqrtf(n2 + 1e-9f);
    float n2v = 0.f;
    #pragma unroll
    for (int d = 0; d < 16; ++d) {
        float vv = vals[d] * f;
        v[(size_t)idx * 16 + d] = vv;
        n2v = fmaf(vv, vv, n2v);
    }
    if (write_out) out[idx] = sqrtf(n2v + 1e-9f);
}

__global__ void __launch_bounds__(320) bb_pass(
    const float* __restrict__ u, const float* __restrict__ W,
    const float* __restrict__ v, float* __restrict__ bb)
{
    int ic = blockIdx.x, bt = blockIdx.y;
    int i0 = ic * 16, b0 = bt * 16;
    int tid = threadIdx.x;
    if (tid >= OD) return;
    int od = tid, o = od >> 4, d = od & 15;
    float vv[16];
    #pragma unroll
    for (int bl = 0; bl < 16; ++bl) vv[bl] = v[(size_t)(b0 + bl) * OD + od];
    for (int il = 0; il < 16; ++il) {
        int i = i0 + il;
        const float* wp = W + (size_t)i * 16 * OD + od;
        float w[16];
        #pragma unroll
        for (int c2 = 0; c2 < 16; ++c2) w[c2] = wp[c2 * OD];
        const float* up = u + ((size_t)i * B_ + b0) * 16;
        #pragma unroll
        for (int bl = 0; bl < 16; ++bl) {
            float uh = 0.f;
            #pragma unroll
            for (int c2 = 0; c2 < 16; ++c2) uh = fmaf(up[bl * 16 + c2], w[c2], uh);
            float p = uh * vv[bl];
            p += __shfl_xor(p, 1);
            p += __shfl_xor(p, 2);
            p += __shfl_xor(p, 4);
            p += __shfl_xor(p, 8);
            if (d == 0) bb[((size_t)(b0 + bl) * NI + i) * NCLASS + o] += p;
        }
    }
}

// ---------------------------------------------------------------------------
extern "C" void kernel_launch(void* const* d_in, const int* in_sizes, int n_in,
                              void* d_out, int out_size, void* d_ws, size_t ws_size,
                              hipStream_t stream)
{
    (void)in_sizes; (void)n_in; (void)out_size; (void)ws_size;
    const int*   word = (const int*)d_in[0];
    const int*   tag  = (const int*)d_in[1];
    const int*   pos1 = (const int*)d_in[2];
    const int*   pos2 = (const int*)d_in[3];
    const float* we   = (const float*)d_in[4];
    const float* te   = (const float*)d_in[5];
    const float* p1e  = (const float*)d_in[6];
    const float* p2e  = (const float*)d_in[7];
    const float* wihf = (const float*)d_in[8];
    const float* whhf = (const float*)d_in[9];
    const float* bihf = (const float*)d_in[10];
    const float* bhhf = (const float*)d_in[11];
    const float* wihb = (const float*)d_in[12];
    const float* whhb = (const float*)d_in[13];
    const float* bihb = (const float*)d_in[14];
    const float* bhhb = (const float*)d_in[15];
    const float* Wc   = (const float*)d_in[16];
    const float* br   = (const float*)d_in[17];

    float* wsp    = (float*)d_ws;
    float* emb    = wsp;                       //  2,048,000
    float* xg     = wsp + 2048000;             // 26,214,400
    float* xf     = xg + 26214400;             //  3,276,800  cluster layout
    float* xb     = xf + 3276800;              //  3,276,800  cluster layout
    float* he     = xb + 3276800;              //     32,768
    float* logits = he + 32768;                //     12,800
    float* att    = logits + 12800;            //     12,800
    int*   e      = (int*)(att + 12800);       //        256 ints
    int*   flags  = e + 256;                   //        256 ints
    // post-scan buffers alias the (dead-after-scan) xg region
    float* x    = xg;                          //  3,276,800  [l][j][b]
    float* u    = xg + 3276800;                //  3,276,800
    float* bb   = xg + 6553600;                //  3,891,200
    float* part = xg + 10444800;               //  3,891,200
    float* s    = xg + 14336000;               //     38,912
    float* v    = s + 38912;                   //     38,912
    float* out  = (float*)d_out;

    const int WLDS_BYTES = 4 * 64 * 528;       // 135168 B dynamic LDS

    emb_gather<<<8000, 256, 0, stream>>>(word, tag, pos1, pos2, we, te, p1e, p2e, emb);
    gemm_xg<<<dim3(8, 100, 2), 256, 0, stream>>>(emb, wihf, bihf, bhhf, wihb, bihb, bhhb, xg);
    zero_flags<<<1, 256, 0, stream>>>(flags);
    {
        (void)hipFuncSetAttribute((const void*)lstm_scan_h,
                                  hipFuncAttributeMaxDynamicSharedMemorySize, WLDS_BYTES);
        const float* xg_c = xg;
        void* args[6] = { (void*)&xg_c, (void*)&whhf, (void*)&whhb,
                          (void*)&xf, (void*)&xb, (void*)&flags };
        hipLaunchCooperativeKernel((const void*)lstm_scan_h, dim3(256), dim3(512),
                                   args, WLDS_BYTES, stream);
    }
    xpose_add<<<12800, 256, 0, stream>>>(xf, xb, x);
    find_entity<<<1, 128, 0, stream>>>(pos1, pos2, e);
    compute_he<<<256, 128, 0, stream>>>(x, e, he);
    att_logits<<<100, 128, 0, stream>>>(x, he, logits);
    att_softmax<<<1, 128, 0, stream>>>(logits, att);
    u_squash<<<1600, 128, 0, stream>>>(x, u);
    bb_init<<<15200, 256, 0, stream>>>(br, bb);
    for (int it = 0; it < 3; ++it) {
        s_pass<<<dim3(100, 8), 320, 0, stream>>>(u, Wc, bb, att, part);
        s_reduce<<<152, 256, 0, stream>>>(part, s);
        squash_v<<<10, 256, 0, stream>>>(s, v, out, (it == 2) ? 1 : 0);
        if (it < 2) bb_pass<<<dim3(100, 8), 320, 0, stream>>>(u, Wc, v, bb);
    }
}